// Round 9
// baseline (235.570 us; speedup 1.0000x reference)
//
#include <hip/hip_runtime.h>

#define B_SZ 4096
#define S_SZ 128
#define XD 5
#define EH 128
#define DH 256
#define DSTEPS 10

typedef short v8s __attribute__((ext_vector_type(8)));
typedef float v4f __attribute__((ext_vector_type(4)));

__device__ __forceinline__ float bf2f(unsigned short u) {
    union { unsigned int i; float f; } v; v.i = ((unsigned int)u) << 16; return v.f;
}
__device__ __forceinline__ unsigned short f2bf(float f) {
    union { float f; unsigned int i; } v; v.f = f;
    unsigned int x = v.i;
    return (unsigned short)((x + 0x7FFFu + ((x >> 16) & 1u)) >> 16);
}
__device__ __forceinline__ float fexp2(float x) { return __builtin_amdgcn_exp2f(x); }
__device__ __forceinline__ float frcp(float x) { return __builtin_amdgcn_rcpf(x); }
// pack 2 f32 -> 1 u32 of 2 bf16 (low word = first operand). HW-verified.
__device__ __forceinline__ unsigned int cvt2bf(float lo, float hi) {
    unsigned int r;
    asm("v_cvt_pk_bf16_f32 %0, %1, %2" : "=v"(r) : "v"(lo), "v"(hi));
    return r;
}

#define SC_S (-1.44269504088896f)   // sigmoid: rcp(1+exp2(SC_S*x))
#define SC_T ( 2.88539008177793f)   // tanh:    1-2*rcp(exp2(SC_T*x)+1)

// ---------------------------------------------------------------- prep
// Decoder weight conversion, hoisted out of enc so the fused kernel has
// no cross-block dependency (stream order guarantees completion).
__global__ __launch_bounds__(256) void prep_kernel(
    const float* __restrict__ dWih,        // [768][129] fp32
    const float* __restrict__ dWhh,        // [768][256] fp32
    unsigned short* __restrict__ wihp,     // out: [768][136] bf16, SCALED
    unsigned short* __restrict__ dWhh_bf)  // out: [768][256] bf16, SCALED
{
    const int gsz = gridDim.x * 256;
    for (int i = blockIdx.x * 256 + threadIdx.x; i < 768 * 256; i += gsz) {
        const float sc = ((i >> 8) < 512) ? SC_S : SC_T;
        dWhh_bf[i] = f2bf(sc * dWhh[i]);
    }
    for (int i = blockIdx.x * 256 + threadIdx.x; i < 768 * 136; i += gsz) {
        int col = i / 136, k = i - col * 136;
        const float sc = (col < 512) ? SC_S : SC_T;
        wihp[i] = (k < 129) ? f2bf(sc * dWih[col * 129 + k]) : (unsigned short)0;
    }
}

// ---------------------------------------------------------------- fused enc+dec
// Block = 16 batch rows, 512 thr (8 waves), 1 block/CU (141 KB LDS).
// Phase 1 = encoder v4 verbatim (measured 104.5us standalone). Its final
// h_128 lands in hb[0] in exactly the layout dec's gi-MFMA consumes ->
// ctex global round-trip deleted.
// Phase 2 = decoder v5 (all-Whh-resident, swapped-operand MFMA), reading
// hb[0] instead of ctex. __launch_bounds__(512,2) -> 256-VGPR budget.
// LDS: dec's gi/wy slabs union over the dead enc xs buffer.
// Measurement intent: ONE dispatch -> dec's cost finally visible in the
// top-5 counters (WRITE>>9MB = spill; FETCH>>12MB = refetch; else latency).
__global__ __launch_bounds__(512, 2)
void fused_kernel(
    const float* __restrict__ x,       // [B][S][5] fp32
    const float* __restrict__ Wih32,   // [384][5] fp32
    const float* __restrict__ Whh32,   // [384][128] fp32
    const float* __restrict__ bih,     // [384] fp32
    const float* __restrict__ bhh,     // [384] fp32
    const float* __restrict__ dbih,    // [768] fp32
    const float* __restrict__ dbhh,    // [768] fp32
    const float* __restrict__ y,       // [B][128] fp32
    const unsigned short* __restrict__ wihp,    // [768][136] bf16, SCALED
    const unsigned short* __restrict__ dWhh_bf, // [768][256] bf16, SCALED
    const float* __restrict__ linW,    // [4][256] fp32
    const float* __restrict__ linb,    // [4] fp32
    float* __restrict__ out)           // [B][S][4] fp32
{
    // uni: enc phase = xs[128][16][8] (32 KB); dec phase = gish+wysh (116 KB)
    __shared__ __align__(16) char uni[118784];
    __shared__ unsigned short hb[2][16][136];      // 8.5 KB (persists to dec gi)
    __shared__ __align__(16) unsigned short zpad[8];
    __shared__ unsigned short hshf[32 * 16 * 8];   // 8 KB dec h state (frag)
    __shared__ unsigned short lwf[32 * 16 * 8];    // 8 KB linW (frag)
    __shared__ float ysh[16][DSTEPS];              // 640 B y slab

    const int tid = threadIdx.x;
    const int bid = blockIdx.x;
    const int wv = tid >> 6;
    const int lane = tid & 63;
    const int n = lane & 15;
    const int kg = lane >> 4;
    const int r0 = bid * 16;

    // ================= PHASE 1: encoder (v4, unchanged logic) =================
    {
        auto xs = (unsigned short (*)[16][8])uni;   // [128][16][8]

        for (int i = tid; i < 2 * 16 * 136; i += 512) ((unsigned short*)hb)[i] = 0;
        if (tid < 8) zpad[tid] = 0;
        for (int i = tid; i < 16 * S_SZ * 8; i += 512) {
            int m = i >> 10;
            int rem = i & 1023;
            int t = rem >> 3;
            int j = rem & 7;
            unsigned short v = 0;
            if (j < XD) v = f2bf(x[(size_t)(r0 + m) * (S_SZ * XD) + t * XD + j]);
            else if (j == XD) v = 0x3F80;          // constant-1 bias carrier
            xs[t][m][j] = v;
        }

        const int colw = wv * 16 + n;
        v8s fw[3][4];
        v8s fx[3];
        #pragma unroll
        for (int g = 0; g < 3; ++g) {
            const float sc = (g < 2) ? SC_S : SC_T;
            const int gcol = g * EH + colw;
            #pragma unroll
            for (int kt = 0; kt < 4; ++kt) {
                const float* p = &Whh32[(size_t)gcol * EH + kt * 32 + kg * 8];
                float4 lo = *(const float4*)p;
                float4 hi = *(const float4*)(p + 4);
                v8s f;
                f[0] = (short)f2bf(sc * lo.x); f[1] = (short)f2bf(sc * lo.y);
                f[2] = (short)f2bf(sc * lo.z); f[3] = (short)f2bf(sc * lo.w);
                f[4] = (short)f2bf(sc * hi.x); f[5] = (short)f2bf(sc * hi.y);
                f[6] = (short)f2bf(sc * hi.z); f[7] = (short)f2bf(sc * hi.w);
                fw[g][kt] = f;
            }
            v8s t = {0, 0, 0, 0, 0, 0, 0, 0};
            if (kg == 0) {
                const float* p = &Wih32[gcol * XD];
                #pragma unroll
                for (int j = 0; j < XD; ++j) t[j] = (short)f2bf(sc * p[j]);
                float b = (g < 2) ? (sc * (bih[gcol] + bhh[gcol]))
                                  : (sc * bih[gcol]);
                t[XD] = (short)f2bf(b);
            }
            fx[g] = t;
        }
        const float bhn = SC_T * bhh[2 * EH + colw];

        const v4f vzero = {0.f, 0.f, 0.f, 0.f};
        float hst[4] = {0.f, 0.f, 0.f, 0.f};
        __syncthreads();

        #pragma unroll 2
        for (int t = 0; t < S_SZ; ++t) {
            const int p = t & 1;
            v8s a[4];
            #pragma unroll
            for (int kt = 0; kt < 4; ++kt)
                a[kt] = *(const v8s*)&hb[p][n][kt * 32 + kg * 8];
            const unsigned short* xsrc = (kg == 0) ? &xs[t][n][0] : &zpad[0];
            v8s ax = *(const v8s*)xsrc;

            v4f accr  = __builtin_amdgcn_mfma_f32_16x16x32_bf16(a[0], fw[0][0], vzero, 0, 0, 0);
            v4f accz  = __builtin_amdgcn_mfma_f32_16x16x32_bf16(a[0], fw[1][0], vzero, 0, 0, 0);
            v4f acchn = __builtin_amdgcn_mfma_f32_16x16x32_bf16(a[0], fw[2][0], vzero, 0, 0, 0);
            #pragma unroll
            for (int kt = 1; kt < 4; ++kt) {
                accr  = __builtin_amdgcn_mfma_f32_16x16x32_bf16(a[kt], fw[0][kt], accr, 0, 0, 0);
                accz  = __builtin_amdgcn_mfma_f32_16x16x32_bf16(a[kt], fw[1][kt], accz, 0, 0, 0);
                acchn = __builtin_amdgcn_mfma_f32_16x16x32_bf16(a[kt], fw[2][kt], acchn, 0, 0, 0);
            }
            accr = __builtin_amdgcn_mfma_f32_16x16x32_bf16(ax, fx[0], accr, 0, 0, 0);
            accz = __builtin_amdgcn_mfma_f32_16x16x32_bf16(ax, fx[1], accz, 0, 0, 0);
            v4f accin = __builtin_amdgcn_mfma_f32_16x16x32_bf16(ax, fx[2], vzero, 0, 0, 0);

            float hnew[4];
            #pragma unroll
            for (int e = 0; e < 4; ++e) {
                float r  = frcp(1.f + fexp2(accr[e]));
                float z  = frcp(1.f + fexp2(accz[e]));
                float nn = 1.f - 2.f * frcp(fexp2(accin[e] + r * (acchn[e] + bhn)) + 1.f);
                float h  = nn + z * (hst[e] - nn);
                hst[e] = h;
                hnew[e] = h;
            }
            const unsigned int pk01 = cvt2bf(hnew[0], hnew[1]);
            const unsigned int pk23 = cvt2bf(hnew[2], hnew[3]);
            hb[1 - p][kg * 4 + 0][colw] = (unsigned short)(pk01 & 0xFFFFu);
            hb[1 - p][kg * 4 + 1][colw] = (unsigned short)(pk01 >> 16);
            hb[1 - p][kg * 4 + 2][colw] = (unsigned short)(pk23 & 0xFFFFu);
            hb[1 - p][kg * 4 + 3][colw] = (unsigned short)(pk23 >> 16);
            __syncthreads();
        }
        // h_128 now lives in hb[0][row][col]; no ctex write needed.
    }

    // ================= PHASE 2: decoder (v5, hb[0] as context) ===============
    {
        const int w = wv;
        const int cbase = w * 32;
        const int rb = r0;
        float* gish = (float*)uni;                 // [512*29] f32
        float* wysh = (float*)(uni + 59392);       // [512*29] f32

        // stage linW into frag layout
        {
            int col = tid >> 5, kgrp = tid & 31;
            unsigned short v8[8];
            #pragma unroll
            for (int j = 0; j < 8; ++j)
                v8[j] = (col < 4) ? f2bf(linW[col * 256 + kgrp * 8 + j]) : (unsigned short)0;
            *(uint4*)&lwf[(kgrp * 16 + col) * 8] = *(uint4*)v8;
        }
        // stage y slab
        if (tid < 16 * DSTEPS) {
            int row = tid / DSTEPS, tt = tid - row * DSTEPS;
            ysh[row][tt] = y[(size_t)(rb + row) * S_SZ + tt];
        }
        // h0 = 1
        for (int i = tid; i < 32 * 16 * 8; i += 512) hshf[i] = 0x3F80;

        // ALL Whh resident: 3 gates x 2 colgroups x 8 K-tiles = 192 VGPRs
        v8s fB[3][2][8];
        #pragma unroll
        for (int g = 0; g < 3; ++g)
            #pragma unroll
            for (int cg = 0; cg < 2; ++cg)
                #pragma unroll
                for (int kt = 0; kt < 8; ++kt)
                    fB[g][cg][kt] = *(const v8s*)
                        &dWhh_bf[(size_t)(g * DH + cbase + cg * 16 + n) * DH + kt * 32 + kg * 8];

        // gi = (Wih . h128^T) via swapped mfma; h128 read straight from hb[0]
        const v4f vzero = {0.f, 0.f, 0.f, 0.f};
        v4f gi[3][2];
        #pragma unroll
        for (int g = 0; g < 3; ++g)
            #pragma unroll
            for (int cg = 0; cg < 2; ++cg) gi[g][cg] = vzero;

        #pragma unroll
        for (int kt = 0; kt < 4; ++kt) {
            v8s actex = *(const v8s*)&hb[0][n][kt * 32 + kg * 8];
            #pragma unroll
            for (int g = 0; g < 3; ++g)
                #pragma unroll
                for (int cg = 0; cg < 2; ++cg) {
                    v8s bw = *(const v8s*)
                        &wihp[(size_t)(g * DH + cbase + cg * 16 + n) * 136 + kt * 32 + kg * 8];
                    gi[g][cg] = __builtin_amdgcn_mfma_f32_16x16x32_bf16(bw, actex, gi[g][cg], 0, 0, 0);
                }
        }

        // biases + wy + bN -> slabs (off critical path; stride 29 = odd)
        #pragma unroll
        for (int g = 0; g < 3; ++g) {
            const float sc = (g < 2) ? SC_S : SC_T;
            #pragma unroll
            for (int cg = 0; cg < 2; ++cg) {
                #pragma unroll
                for (int e = 0; e < 4; ++e) {
                    const int col = cbase + cg * 16 + kg * 4 + e;
                    const int gcol = g * DH + col;
                    float bb = sc * (dbih[gcol] + ((g < 2) ? dbhh[gcol] : 0.f));
                    gi[g][cg][e] += bb;
                    wysh[tid * 29 + (g * 2 + cg) * 4 + e] = bf2f(wihp[(size_t)gcol * 136 + 128]);
                }
            }
        }
        #pragma unroll
        for (int g = 0; g < 3; ++g)
            #pragma unroll
            for (int cg = 0; cg < 2; ++cg)
                *(v4f*)&gish[tid * 29 + (g * 2 + cg) * 4] = gi[g][cg];
        #pragma unroll
        for (int e = 0; e < 4; ++e) {
            gish[tid * 29 + 24 + e] = SC_T * dbhh[2 * DH + cbase + 0 * 16 + kg * 4 + e];
            wysh[tid * 29 + 24 + e] = SC_T * dbhh[2 * DH + cbase + 1 * 16 + kg * 4 + e];
        }

        const float4 lb4 = *(const float4*)linb;
        float hprev[2][4];
        #pragma unroll
        for (int cg = 0; cg < 2; ++cg)
            #pragma unroll
            for (int e = 0; e < 4; ++e) hprev[cg][e] = 1.0f;

        __syncthreads();

        for (int t = 0; t < DSTEPS; ++t) {
            const float yv = ysh[n][t];

            v4f ar[2], az[2], an[2];
            #pragma unroll
            for (int cg = 0; cg < 2; ++cg) { ar[cg] = vzero; az[cg] = vzero; an[cg] = vzero; }

            #pragma unroll
            for (int kt = 0; kt < 8; ++kt) {
                v8s a = *(const v8s*)&hshf[((kt * 4 + kg) * 16 + n) * 8];
                #pragma unroll
                for (int cg = 0; cg < 2; ++cg) {
                    ar[cg] = __builtin_amdgcn_mfma_f32_16x16x32_bf16(fB[0][cg][kt], a, ar[cg], 0, 0, 0);
                    az[cg] = __builtin_amdgcn_mfma_f32_16x16x32_bf16(fB[1][cg][kt], a, az[cg], 0, 0, 0);
                    an[cg] = __builtin_amdgcn_mfma_f32_16x16x32_bf16(fB[2][cg][kt], a, an[cg], 0, 0, 0);
                }
            }
            __syncthreads();   // all reads of h_t complete

            #pragma unroll
            for (int cg = 0; cg < 2; ++cg) {
                v4f giR = *(const v4f*)&gish[tid * 29 + (0 * 2 + cg) * 4];
                v4f giZ = *(const v4f*)&gish[tid * 29 + (1 * 2 + cg) * 4];
                v4f giN = *(const v4f*)&gish[tid * 29 + (2 * 2 + cg) * 4];
                v4f wyR = *(const v4f*)&wysh[tid * 29 + (0 * 2 + cg) * 4];
                v4f wyZ = *(const v4f*)&wysh[tid * 29 + (1 * 2 + cg) * 4];
                v4f wyN = *(const v4f*)&wysh[tid * 29 + (2 * 2 + cg) * 4];
                v4f bN  = (cg == 0) ? *(const v4f*)&gish[tid * 29 + 24]
                                    : *(const v4f*)&wysh[tid * 29 + 24];
                float hh[4];
                #pragma unroll
                for (int e = 0; e < 4; ++e) {
                    float r  = frcp(1.f + fexp2(giR[e] + yv * wyR[e] + ar[cg][e]));
                    float z  = frcp(1.f + fexp2(giZ[e] + yv * wyZ[e] + az[cg][e]));
                    float nn = 1.f - 2.f * frcp(
                        fexp2(giN[e] + yv * wyN[e] + r * (an[cg][e] + bN[e])) + 1.f);
                    float h  = nn + z * (hprev[cg][e] - nn);
                    hprev[cg][e] = h;
                    hh[e] = h;
                }
                const unsigned int p01 = cvt2bf(hh[0], hh[1]);
                const unsigned int p23 = cvt2bf(hh[2], hh[3]);
                const int base = cbase + cg * 16 + kg * 4;
                const int idx = (((base >> 3) * 16) + n) * 8 + (base & 7);
                *(uint2*)&hshf[idx] = (uint2){p01, p23};
            }
            __syncthreads();   // h_{t+1} visible

            if (w == (t & 7)) {   // out-proj, rotated across waves
                v4f o4 = vzero;
                #pragma unroll
                for (int kt = 0; kt < 8; ++kt) {
                    v8s a = *(const v8s*)&hshf[((kt * 4 + kg) * 16 + n) * 8];
                    v8s b = *(const v8s*)&lwf[((kt * 4 + kg) * 16 + n) * 8];
                    o4 = __builtin_amdgcn_mfma_f32_16x16x32_bf16(b, a, o4, 0, 0, 0);
                }
                if (kg == 0) {
                    float4 ov = {o4[0] + lb4.x, o4[1] + lb4.y, o4[2] + lb4.z, o4[3] + lb4.w};
                    *(float4*)&out[(size_t)(rb + n) * (S_SZ * 4) + t * 4] = ov;
                }
            }
        }

        // tail pad: out[:, 10:, :] = 1.0
        for (int j = tid; j < 16 * 512; j += 512) {
            int row = j >> 9, c = j & 511;
            if (c >= DSTEPS * 4) out[(size_t)(rb + row) * 512 + c] = 1.0f;
        }
    }
}

// ---------------------------------------------------------------- launch
extern "C" void kernel_launch(void* const* d_in, const int* in_sizes, int n_in,
                              void* d_out, int out_size, void* d_ws, size_t ws_size,
                              hipStream_t stream)
{
    const float* x    = (const float*)d_in[0];
    const float* y    = (const float*)d_in[1];
    const float* eWih = (const float*)d_in[2];
    const float* eWhh = (const float*)d_in[3];
    const float* ebih = (const float*)d_in[4];
    const float* ebhh = (const float*)d_in[5];
    const float* dWih = (const float*)d_in[6];
    const float* dWhh = (const float*)d_in[7];
    const float* dbih = (const float*)d_in[8];
    const float* dbhh = (const float*)d_in[9];
    const float* linW = (const float*)d_in[10];
    const float* linb = (const float*)d_in[11];
    float* out = (float*)d_out;

    char* ws = (char*)d_ws;
    // ws layout (bytes):
    //   wihp     @ 0      : 768*136*2 = 208896
    //   dWhh_bf  @ 208896 : 768*256*2 = 393216
    unsigned short* wihp    = (unsigned short*)(ws);
    unsigned short* dWhh_bf = (unsigned short*)(ws + 208896);

    prep_kernel<<<256, 256, 0, stream>>>(dWih, dWhh, wihp, dWhh_bf);
    fused_kernel<<<256, 512, 0, stream>>>(x, eWih, eWhh, ebih, ebhh,
                                          dbih, dbhh, y, wihp, dWhh_bf,
                                          linW, linb, out);
}

// Round 10
// 208.114 us; speedup vs baseline: 1.1319x; 1.1319x over previous
//
#include <hip/hip_runtime.h>

#define B_SZ 4096
#define S_SZ 128
#define XD 5
#define EH 128
#define DH 256
#define DSTEPS 10

typedef short v8s __attribute__((ext_vector_type(8)));
typedef float v4f __attribute__((ext_vector_type(4)));

__device__ __forceinline__ float bf2f(unsigned short u) {
    union { unsigned int i; float f; } v; v.i = ((unsigned int)u) << 16; return v.f;
}
__device__ __forceinline__ unsigned short f2bf(float f) {
    union { float f; unsigned int i; } v; v.f = f;
    unsigned int x = v.i;
    return (unsigned short)((x + 0x7FFFu + ((x >> 16) & 1u)) >> 16);
}
__device__ __forceinline__ float fexp2(float x) { return __builtin_amdgcn_exp2f(x); }
__device__ __forceinline__ float frcp(float x) { return __builtin_amdgcn_rcpf(x); }
// pack 2 f32 -> 1 u32 of 2 bf16 (low word = first operand). HW-verified.
__device__ __forceinline__ unsigned int cvt2bf(float lo, float hi) {
    unsigned int r;
    asm("v_cvt_pk_bf16_f32 %0, %1, %2" : "=v"(r) : "v"(lo), "v"(hi));
    return r;
}

#define SC_S (-1.44269504088896f)   // sigmoid: rcp(1+exp2(SC_S*x))
#define SC_T ( 2.88539008177793f)   // tanh:    1-2*rcp(exp2(SC_T*x)+1)

// ---------------------------------------------------------------- prep
__global__ __launch_bounds__(256) void prep_kernel(
    const float* __restrict__ dWih,        // [768][129] fp32
    const float* __restrict__ dWhh,        // [768][256] fp32
    unsigned short* __restrict__ wihp,     // out: [768][136] bf16, SCALED
    unsigned short* __restrict__ dWhh_bf)  // out: [768][256] bf16, SCALED
{
    const int gsz = gridDim.x * 256;
    for (int i = blockIdx.x * 256 + threadIdx.x; i < 768 * 256; i += gsz) {
        const float sc = ((i >> 8) < 512) ? SC_S : SC_T;
        dWhh_bf[i] = f2bf(sc * dWhh[i]);
    }
    for (int i = blockIdx.x * 256 + threadIdx.x; i < 768 * 136; i += gsz) {
        int col = i / 136, k = i - col * 136;
        const float sc = (col < 512) ? SC_S : SC_T;
        wihp[i] = (k < 129) ? f2bf(sc * dWih[col * 129 + k]) : (unsigned short)0;
    }
}

// ---------------------------------------------------------------- fused enc+dec v2
// 256 blocks x 1024 thr (16 waves), 1 block/CU (141 KB LDS), 128-VGPR cap.
// R9 counters: VGPR_Count=128 (launch_bounds(512,2) did NOT unlock 256) +
// WRITE_SIZE 21MB vs 8.4MB output = fB[3][2][8] (192 regs) spilling.
// Fix: 16 waves, each owns 16 cols of EACH gate -> fB[3][8] = 96 VGPRs.
// Step live-set ~125 regs: fits the 128 cap -> no spill, no launch-bounds
// dependence. Enc phase identical logic, guarded wv<8 (waves 8-15 idle at
// barriers; same 8 working waves/CU as the measured 104.5us standalone).
// Dec constants (gi/wy/bN) in LDS slab stride 29 (coprime 32 -> no bank
// conflicts on scalar reads).
__global__ __launch_bounds__(1024)
void fused_kernel(
    const float* __restrict__ x,       // [B][S][5] fp32
    const float* __restrict__ Wih32,   // [384][5] fp32
    const float* __restrict__ Whh32,   // [384][128] fp32
    const float* __restrict__ bih,     // [384] fp32
    const float* __restrict__ bhh,     // [384] fp32
    const float* __restrict__ dbih,    // [768] fp32
    const float* __restrict__ dbhh,    // [768] fp32
    const float* __restrict__ y,       // [B][128] fp32
    const unsigned short* __restrict__ wihp,    // [768][136] bf16, SCALED
    const unsigned short* __restrict__ dWhh_bf, // [768][256] bf16, SCALED
    const float* __restrict__ linW,    // [4][256] fp32
    const float* __restrict__ linb,    // [4] fp32
    float* __restrict__ out)           // [B][S][4] fp32
{
    // uni: enc = xs[128][16][8] (32 KB); dec = const slab 1024*29 f32 (116 KB)
    __shared__ __align__(16) char uni[118784];
    __shared__ unsigned short hb[2][16][136];      // 8.5 KB (h_128 -> dec gi)
    __shared__ __align__(16) unsigned short zpad[8];
    __shared__ unsigned short hshf[32 * 16 * 8];   // 8 KB dec h state (frag)
    __shared__ unsigned short lwf[32 * 16 * 8];    // 8 KB linW (frag)
    __shared__ float ysh[16][DSTEPS];              // 640 B y slab

    const int tid = threadIdx.x;
    const int bid = blockIdx.x;
    const int wv = tid >> 6;        // 0..15
    const int lane = tid & 63;
    const int n = lane & 15;
    const int kg = lane >> 4;
    const int r0 = bid * 16;

    // ================= PHASE 1: encoder (v4 logic, waves 0-7) ================
    {
        auto xs = (unsigned short (*)[16][8])uni;   // [128][16][8]

        for (int i = tid; i < 2 * 16 * 136; i += 1024) ((unsigned short*)hb)[i] = 0;
        if (tid < 8) zpad[tid] = 0;
        for (int i = tid; i < 16 * S_SZ * 8; i += 1024) {
            int m = i >> 10;
            int rem = i & 1023;
            int t = rem >> 3;
            int j = rem & 7;
            unsigned short v = 0;
            if (j < XD) v = f2bf(x[(size_t)(r0 + m) * (S_SZ * XD) + t * XD + j]);
            else if (j == XD) v = 0x3F80;          // constant-1 bias carrier
            xs[t][m][j] = v;
        }

        const int colw = wv * 16 + n;              // valid for wv<8
        v8s fw[3][4];
        v8s fx[3];
        float bhn = 0.f;
        if (wv < 8) {
            #pragma unroll
            for (int g = 0; g < 3; ++g) {
                const float sc = (g < 2) ? SC_S : SC_T;
                const int gcol = g * EH + colw;
                #pragma unroll
                for (int kt = 0; kt < 4; ++kt) {
                    const float* p = &Whh32[(size_t)gcol * EH + kt * 32 + kg * 8];
                    float4 lo = *(const float4*)p;
                    float4 hi = *(const float4*)(p + 4);
                    v8s f;
                    f[0] = (short)f2bf(sc * lo.x); f[1] = (short)f2bf(sc * lo.y);
                    f[2] = (short)f2bf(sc * lo.z); f[3] = (short)f2bf(sc * lo.w);
                    f[4] = (short)f2bf(sc * hi.x); f[5] = (short)f2bf(sc * hi.y);
                    f[6] = (short)f2bf(sc * hi.z); f[7] = (short)f2bf(sc * hi.w);
                    fw[g][kt] = f;
                }
                v8s t = {0, 0, 0, 0, 0, 0, 0, 0};
                if (kg == 0) {
                    const float* p = &Wih32[gcol * XD];
                    #pragma unroll
                    for (int j = 0; j < XD; ++j) t[j] = (short)f2bf(sc * p[j]);
                    float b = (g < 2) ? (sc * (bih[gcol] + bhh[gcol]))
                                      : (sc * bih[gcol]);
                    t[XD] = (short)f2bf(b);
                }
                fx[g] = t;
            }
            bhn = SC_T * bhh[2 * EH + colw];
        }

        const v4f vzero = {0.f, 0.f, 0.f, 0.f};
        float hst[4] = {0.f, 0.f, 0.f, 0.f};
        __syncthreads();

        #pragma unroll 2
        for (int t = 0; t < S_SZ; ++t) {
            const int p = t & 1;
            if (wv < 8) {
                v8s a[4];
                #pragma unroll
                for (int kt = 0; kt < 4; ++kt)
                    a[kt] = *(const v8s*)&hb[p][n][kt * 32 + kg * 8];
                const unsigned short* xsrc = (kg == 0) ? &xs[t][n][0] : &zpad[0];
                v8s ax = *(const v8s*)xsrc;

                v4f accr  = __builtin_amdgcn_mfma_f32_16x16x32_bf16(a[0], fw[0][0], vzero, 0, 0, 0);
                v4f accz  = __builtin_amdgcn_mfma_f32_16x16x32_bf16(a[0], fw[1][0], vzero, 0, 0, 0);
                v4f acchn = __builtin_amdgcn_mfma_f32_16x16x32_bf16(a[0], fw[2][0], vzero, 0, 0, 0);
                #pragma unroll
                for (int kt = 1; kt < 4; ++kt) {
                    accr  = __builtin_amdgcn_mfma_f32_16x16x32_bf16(a[kt], fw[0][kt], accr, 0, 0, 0);
                    accz  = __builtin_amdgcn_mfma_f32_16x16x32_bf16(a[kt], fw[1][kt], accz, 0, 0, 0);
                    acchn = __builtin_amdgcn_mfma_f32_16x16x32_bf16(a[kt], fw[2][kt], acchn, 0, 0, 0);
                }
                accr = __builtin_amdgcn_mfma_f32_16x16x32_bf16(ax, fx[0], accr, 0, 0, 0);
                accz = __builtin_amdgcn_mfma_f32_16x16x32_bf16(ax, fx[1], accz, 0, 0, 0);
                v4f accin = __builtin_amdgcn_mfma_f32_16x16x32_bf16(ax, fx[2], vzero, 0, 0, 0);

                float hnew[4];
                #pragma unroll
                for (int e = 0; e < 4; ++e) {
                    float r  = frcp(1.f + fexp2(accr[e]));
                    float z  = frcp(1.f + fexp2(accz[e]));
                    float nn = 1.f - 2.f * frcp(fexp2(accin[e] + r * (acchn[e] + bhn)) + 1.f);
                    float h  = nn + z * (hst[e] - nn);
                    hst[e] = h;
                    hnew[e] = h;
                }
                const unsigned int pk01 = cvt2bf(hnew[0], hnew[1]);
                const unsigned int pk23 = cvt2bf(hnew[2], hnew[3]);
                hb[1 - p][kg * 4 + 0][colw] = (unsigned short)(pk01 & 0xFFFFu);
                hb[1 - p][kg * 4 + 1][colw] = (unsigned short)(pk01 >> 16);
                hb[1 - p][kg * 4 + 2][colw] = (unsigned short)(pk23 & 0xFFFFu);
                hb[1 - p][kg * 4 + 3][colw] = (unsigned short)(pk23 >> 16);
            }
            __syncthreads();
        }
        // h_128 lives in hb[0][row][col].
    }

    // ================= PHASE 2: decoder (16 waves x 16 cols/gate) ============
    {
        const int w = wv;
        const int colb = w * 16;                   // this wave's 16 cols (per gate)
        const int rb = r0;
        float* gwsh = (float*)uni;                 // [1024*29] f32 const slab

        // stage linW into frag layout (first 512 threads only)
        if (tid < 512) {
            int col = tid >> 5, kgrp = tid & 31;
            unsigned short v8[8];
            #pragma unroll
            for (int j = 0; j < 8; ++j)
                v8[j] = (col < 4) ? f2bf(linW[col * 256 + kgrp * 8 + j]) : (unsigned short)0;
            *(uint4*)&lwf[(kgrp * 16 + col) * 8] = *(uint4*)v8;
        }
        // stage y slab
        if (tid < 16 * DSTEPS) {
            int row = tid / DSTEPS, tt = tid - row * DSTEPS;
            ysh[row][tt] = y[(size_t)(rb + row) * S_SZ + tt];
        }
        // h0 = 1
        for (int i = tid; i < 32 * 16 * 8; i += 1024) hshf[i] = 0x3F80;

        // resident Whh for this wave: 3 gates x 8 K-tiles = 96 VGPRs
        v8s fB[3][8];
        #pragma unroll
        for (int g = 0; g < 3; ++g)
            #pragma unroll
            for (int kt = 0; kt < 8; ++kt)
                fB[g][kt] = *(const v8s*)
                    &dWhh_bf[(size_t)(g * DH + colb + n) * DH + kt * 32 + kg * 8];

        // gi = (Wih . h128^T) via swapped mfma: lane (n,kg) elem e ->
        // (gatecol colb+kg*4+e, batchrow n). h128 straight from hb[0].
        const v4f vzero = {0.f, 0.f, 0.f, 0.f};
        v4f gi[3];
        #pragma unroll
        for (int g = 0; g < 3; ++g) gi[g] = vzero;

        #pragma unroll
        for (int kt = 0; kt < 4; ++kt) {
            v8s actex = *(const v8s*)&hb[0][n][kt * 32 + kg * 8];
            #pragma unroll
            for (int g = 0; g < 3; ++g) {
                v8s bw = *(const v8s*)
                    &wihp[(size_t)(g * DH + colb + n) * 136 + kt * 32 + kg * 8];
                gi[g] = __builtin_amdgcn_mfma_f32_16x16x32_bf16(bw, actex, gi[g], 0, 0, 0);
            }
        }

        // slab layout per thread (stride 29): [0..11] gi, [12..23] wy, [24..27] bN
        #pragma unroll
        for (int g = 0; g < 3; ++g) {
            const float sc = (g < 2) ? SC_S : SC_T;
            #pragma unroll
            for (int e = 0; e < 4; ++e) {
                const int gcol = g * DH + colb + kg * 4 + e;
                gi[g][e] += sc * (dbih[gcol] + ((g < 2) ? dbhh[gcol] : 0.f));
                gwsh[tid * 29 + 12 + g * 4 + e] = bf2f(wihp[(size_t)gcol * 136 + 128]);
            }
            *(v4f*)&gwsh[tid * 29 + g * 4] = gi[g];
        }
        #pragma unroll
        for (int e = 0; e < 4; ++e)
            gwsh[tid * 29 + 24 + e] = SC_T * dbhh[2 * DH + colb + kg * 4 + e];

        float hprev[4] = {1.f, 1.f, 1.f, 1.f};
        __syncthreads();

        for (int t = 0; t < DSTEPS; ++t) {
            const float yv = ysh[n][t];

            v4f ar = vzero, az = vzero, an = vzero;
            #pragma unroll
            for (int kt = 0; kt < 8; ++kt) {
                v8s a = *(const v8s*)&hshf[((kt * 4 + kg) * 16 + n) * 8];
                ar = __builtin_amdgcn_mfma_f32_16x16x32_bf16(fB[0][kt], a, ar, 0, 0, 0);
                az = __builtin_amdgcn_mfma_f32_16x16x32_bf16(fB[1][kt], a, az, 0, 0, 0);
                an = __builtin_amdgcn_mfma_f32_16x16x32_bf16(fB[2][kt], a, an, 0, 0, 0);
            }
            __syncthreads();   // all reads of h_t complete

            float hh[4];
            #pragma unroll
            for (int e = 0; e < 4; ++e) {
                const float giR = gwsh[tid * 29 + 0 + e];
                const float giZ = gwsh[tid * 29 + 4 + e];
                const float giN = gwsh[tid * 29 + 8 + e];
                const float wyR = gwsh[tid * 29 + 12 + e];
                const float wyZ = gwsh[tid * 29 + 16 + e];
                const float wyN = gwsh[tid * 29 + 20 + e];
                const float bN  = gwsh[tid * 29 + 24 + e];
                float r  = frcp(1.f + fexp2(giR + yv * wyR + ar[e]));
                float z  = frcp(1.f + fexp2(giZ + yv * wyZ + az[e]));
                float nn = 1.f - 2.f * frcp(
                    fexp2(giN + yv * wyN + r * (an[e] + bN)) + 1.f);
                float h  = nn + z * (hprev[e] - nn);
                hprev[e] = h;
                hh[e] = h;
            }
            const unsigned int p01 = cvt2bf(hh[0], hh[1]);
            const unsigned int p23 = cvt2bf(hh[2], hh[3]);
            const int base = colb + kg * 4;        // 4 consecutive cols
            const int idx = (((base >> 3) * 16) + n) * 8 + (base & 7);
            *(uint2*)&hshf[idx] = (uint2){p01, p23};
            __syncthreads();   // h_{t+1} visible

            if (w == t) {      // out-proj, rotated across waves (t<10<16)
                v4f o4 = vzero;
                #pragma unroll
                for (int kt = 0; kt < 8; ++kt) {
                    v8s a = *(const v8s*)&hshf[((kt * 4 + kg) * 16 + n) * 8];
                    v8s b = *(const v8s*)&lwf[((kt * 4 + kg) * 16 + n) * 8];
                    o4 = __builtin_amdgcn_mfma_f32_16x16x32_bf16(b, a, o4, 0, 0, 0);
                }
                if (kg == 0) {
                    const float4 lb4 = *(const float4*)linb;
                    float4 ov = {o4[0] + lb4.x, o4[1] + lb4.y, o4[2] + lb4.z, o4[3] + lb4.w};
                    *(float4*)&out[(size_t)(rb + n) * (S_SZ * 4) + t * 4] = ov;
                }
            }
        }

        // tail pad: out[:, 10:, :] = 1.0
        for (int j = tid; j < 16 * 512; j += 1024) {
            int row = j >> 9, c = j & 511;
            if (c >= DSTEPS * 4) out[(size_t)(rb + row) * 512 + c] = 1.0f;
        }
    }
}

// ---------------------------------------------------------------- launch
extern "C" void kernel_launch(void* const* d_in, const int* in_sizes, int n_in,
                              void* d_out, int out_size, void* d_ws, size_t ws_size,
                              hipStream_t stream)
{
    const float* x    = (const float*)d_in[0];
    const float* y    = (const float*)d_in[1];
    const float* eWih = (const float*)d_in[2];
    const float* eWhh = (const float*)d_in[3];
    const float* ebih = (const float*)d_in[4];
    const float* ebhh = (const float*)d_in[5];
    const float* dWih = (const float*)d_in[6];
    const float* dWhh = (const float*)d_in[7];
    const float* dbih = (const float*)d_in[8];
    const float* dbhh = (const float*)d_in[9];
    const float* linW = (const float*)d_in[10];
    const float* linb = (const float*)d_in[11];
    float* out = (float*)d_out;

    char* ws = (char*)d_ws;
    // ws layout (bytes):
    //   wihp     @ 0      : 768*136*2 = 208896
    //   dWhh_bf  @ 208896 : 768*256*2 = 393216
    unsigned short* wihp    = (unsigned short*)(ws);
    unsigned short* dWhh_bf = (unsigned short*)(ws + 208896);

    prep_kernel<<<256, 256, 0, stream>>>(dWih, dWhh, wihp, dWhh_bf);
    fused_kernel<<<256, 1024, 0, stream>>>(x, eWih, eWhh, ebih, ebhh,
                                           dbih, dbhh, y, wihp, dWhh_bf,
                                           linW, linb, out);
}